// Round 2
// baseline (386.080 us; speedup 1.0000x reference)
//
#include <hip/hip_runtime.h>
#include <math.h>

// Problem constants (KimiLinearKDADecode): HK=HV=32, D=128, K=4, B=128
#define NHK   32
#define NHV   32
#define DDIM  128
#define NB    128
#define QKVC  12288   // (2*HK+HV)*D

__device__ __forceinline__ float sigmoid_f(float x) { return 1.0f / (1.0f + expf(-x)); }
__device__ __forceinline__ float silu_f(float x)    { return x * sigmoid_f(x); }
__device__ __forceinline__ float softplus_f(float x){ return (x > 20.0f) ? x : log1pf(expf(x)); }

// One block per (b, h). 256 threads.
//  o[b,h,v] = sum_k qn[k]*eg[k]*S0[k,v]
//           + (qn.kn) * (v[v] - sum_k kn[k]*eg[k]*S0[k,v]) * sigmoid(beta)
// Pipeline: issue ALL global loads up front (prologue inputs, then the 16
// float4 S rows into registers), then do the barrier-light prologue while
// the S stream is in flight.
__global__ __launch_bounds__(256)
void kda_decode_kernel(const float* __restrict__ mixed,    // (B, 12288)
                       const float* __restrict__ fgate,    // (B, 4096)
                       const float* __restrict__ beta,     // (B, 32)
                       const float* __restrict__ cstate,   // (B, 12288, 3)
                       const float* __restrict__ cweight,  // (12288, 4)
                       const float* __restrict__ ssm,      // (B, 32, 128, 128)
                       const float* __restrict__ A_log,    // (32,)
                       const float* __restrict__ dt_bias,  // (4096,)
                       float* __restrict__ out)            // (B, 32, 128)
{
    const int bh  = blockIdx.x;
    const int b   = bh >> 5;
    const int h   = bh & 31;
    const int tid = threadIdx.x;

    __shared__ float w_q[DDIM], w_k[DDIM], v_s[DDIM];
    __shared__ float pq[8][DDIM], pk[8][DDIM];
    __shared__ float part[4][3];

    // ---- phase 0: issue prologue loads (tid<128 lanes) ----
    float cs_q[3], cs_k[3], cs_v[3];
    float4 cw_q = {0,0,0,0}, cw_k = {0,0,0,0}, cw_v = {0,0,0,0};
    float mx_q = 0.f, mx_k = 0.f, mx_v = 0.f, fg = 0.f, dtb = 0.f;
    cs_q[0]=cs_q[1]=cs_q[2]=0.f; cs_k[0]=cs_k[1]=cs_k[2]=0.f; cs_v[0]=cs_v[1]=cs_v[2]=0.f;

    const float betav = beta[b * NHV + h];   // broadcast load
    const float alog  = A_log[h];            // broadcast load

    if (tid < DDIM) {
        const int cq = h * DDIM + tid;
        const int ck = (NHK + h) * DDIM + tid;
        const int cv = (2 * NHK + h) * DDIM + tid;
        const size_t b3 = (size_t)b * QKVC * 3;
        const size_t b1 = (size_t)b * QKVC;

        #pragma unroll
        for (int j = 0; j < 3; ++j) {
            cs_q[j] = cstate[b3 + (size_t)cq * 3 + j];
            cs_k[j] = cstate[b3 + (size_t)ck * 3 + j];
            cs_v[j] = cstate[b3 + (size_t)cv * 3 + j];
        }
        cw_q = *reinterpret_cast<const float4*>(cweight + (size_t)cq * 4);
        cw_k = *reinterpret_cast<const float4*>(cweight + (size_t)ck * 4);
        cw_v = *reinterpret_cast<const float4*>(cweight + (size_t)cv * 4);
        mx_q = mixed[b1 + cq];
        mx_k = mixed[b1 + ck];
        mx_v = mixed[b1 + cv];
        fg   = fgate[(size_t)b * (NHV * DDIM) + h * DDIM + tid];
        dtb  = dt_bias[h * DDIM + tid];
    }

    // ---- phase 1: issue the full S stream into registers (in flight during prologue) ----
    const float* Sb = ssm + (size_t)bh * (DDIM * DDIM);
    const int g8 = tid >> 5;          // k-group 0..7 (16 rows each)
    const int v4 = (tid & 31) * 4;    // 4 consecutive columns per lane
    float4 sreg[16];
    #pragma unroll
    for (int kk = 0; kk < 16; ++kk)
        sreg[kk] = *reinterpret_cast<const float4*>(Sb + (size_t)(g8 * 16 + kk) * DDIM + v4);

    // ---- phase 2: conv + SiLU ----
    float xq = 0.f, xk = 0.f, xv = 0.f;
    if (tid < DDIM) {
        xq = silu_f(cs_q[0]*cw_q.x + cs_q[1]*cw_q.y + cs_q[2]*cw_q.z + mx_q*cw_q.w);
        xk = silu_f(cs_k[0]*cw_k.x + cs_k[1]*cw_k.y + cs_k[2]*cw_k.z + mx_k*cw_k.w);
        xv = silu_f(cs_v[0]*cw_v.x + cs_v[1]*cw_v.y + cs_v[2]*cw_v.z + mx_v*cw_v.w);
    }

    // ---- phase 3: wave-level reductions (|q|^2, |k|^2, q.k), 1 barrier ----
    float a0 = xq * xq, a1 = xk * xk, a2 = xq * xk;
    #pragma unroll
    for (int off = 32; off; off >>= 1) {
        a0 += __shfl_xor(a0, off);
        a1 += __shfl_xor(a1, off);
        a2 += __shfl_xor(a2, off);
    }
    const int wid = tid >> 6;
    if ((tid & 63) == 0) { part[wid][0] = a0; part[wid][1] = a1; part[wid][2] = a2; }
    __syncthreads();
    const float q2  = part[0][0] + part[1][0];   // waves 2,3 contribute zeros
    const float k2  = part[0][1] + part[1][1];
    const float qkd = part[0][2] + part[1][2];

    const float dscale = 0.08838834764831845f;   // 1/sqrt(128)
    const float rq = rsqrtf(q2 + 1e-6f);
    const float rk = rsqrtf(k2 + 1e-6f);
    const float qk = qkd * rq * rk * dscale;     // qn . kn
    const float bsig = sigmoid_f(betav);

    if (tid < DDIM) {
        const float g  = -expf(alog) * softplus_f(fg + dtb);
        const float eg = expf(g);
        w_q[tid] = xq * rq * dscale * eg;
        w_k[tid] = xk * rk * eg;
        v_s[tid] = xv;
    }
    __syncthreads();

    // ---- phase 4: FMA over the in-register S rows ----
    float4 accq = {0.f, 0.f, 0.f, 0.f};
    float4 acck = {0.f, 0.f, 0.f, 0.f};
    #pragma unroll
    for (int kk = 0; kk < 16; ++kk) {
        const int k = g8 * 16 + kk;
        const float wq = w_q[k];   // broadcast LDS read (conflict-free)
        const float wk = w_k[k];
        const float4 s = sreg[kk];
        accq.x = fmaf(wq, s.x, accq.x); accq.y = fmaf(wq, s.y, accq.y);
        accq.z = fmaf(wq, s.z, accq.z); accq.w = fmaf(wq, s.w, accq.w);
        acck.x = fmaf(wk, s.x, acck.x); acck.y = fmaf(wk, s.y, acck.y);
        acck.z = fmaf(wk, s.z, acck.z); acck.w = fmaf(wk, s.w, acck.w);
    }
    *reinterpret_cast<float4*>(&pq[g8][v4]) = accq;
    *reinterpret_cast<float4*>(&pk[g8][v4]) = acck;
    __syncthreads();

    // ---- epilogue: combine partials, delta-rule correction, store ----
    if (tid < DDIM) {
        float aq = 0.f, ak = 0.f;
        #pragma unroll
        for (int g = 0; g < 8; ++g) { aq += pq[g][tid]; ak += pk[g][tid]; }
        const float o = aq + qk * (v_s[tid] - ak) * bsig;
        out[(size_t)bh * DDIM + tid] = o;
    }
}

extern "C" void kernel_launch(void* const* d_in, const int* in_sizes, int n_in,
                              void* d_out, int out_size, void* d_ws, size_t ws_size,
                              hipStream_t stream) {
    const float* mixed   = (const float*)d_in[0];
    const float* fgate   = (const float*)d_in[1];
    const float* beta    = (const float*)d_in[2];
    const float* cstate  = (const float*)d_in[3];
    const float* cweight = (const float*)d_in[4];
    const float* ssm     = (const float*)d_in[5];
    const float* A_log   = (const float*)d_in[6];
    const float* dt_bias = (const float*)d_in[7];
    float* out = (float*)d_out;

    kda_decode_kernel<<<NB * NHV, 256, 0, stream>>>(
        mixed, fgate, beta, cstate, cweight, ssm, A_log, dt_bias, out);
}

// Round 3
// 364.694 us; speedup vs baseline: 1.0586x; 1.0586x over previous
//
#include <hip/hip_runtime.h>
#include <math.h>

// Problem constants (KimiLinearKDADecode): HK=HV=32, D=128, K=4, B=128
#define NHK   32
#define NHV   32
#define DDIM  128
#define NB    128
#define QKVC  12288   // (2*HK+HV)*D

typedef float f32x4 __attribute__((ext_vector_type(4)));

__device__ __forceinline__ float sigmoid_f(float x) { return 1.0f / (1.0f + expf(-x)); }
__device__ __forceinline__ float silu_f(float x)    { return x * sigmoid_f(x); }
__device__ __forceinline__ float softplus_f(float x){ return (x > 20.0f) ? x : log1pf(expf(x)); }

// One block per (b, h). 256 threads.
//  o[b,h,v] = sum_k qn[k]*eg[k]*S0[k,v]
//           + (qn.kn) * (v[v] - sum_k kn[k]*eg[k]*S0[k,v]) * sigmoid(beta)
// S-stream shaped like the 6.3 TB/s copy bench: per iteration each wave reads
// one contiguous 1 KB line (block reads 4 KB contiguous), unroll-4 pipeline,
// nontemporal loads (S is read exactly once — skip L2 allocation).
__global__ __launch_bounds__(256, 4)
void kda_decode_kernel(const float* __restrict__ mixed,    // (B, 12288)
                       const float* __restrict__ fgate,    // (B, 4096)
                       const float* __restrict__ beta,     // (B, 32)
                       const float* __restrict__ cstate,   // (B, 12288, 3)
                       const float* __restrict__ cweight,  // (12288, 4)
                       const float* __restrict__ ssm,      // (B, 32, 128, 128)
                       const float* __restrict__ A_log,    // (32,)
                       const float* __restrict__ dt_bias,  // (4096,)
                       float* __restrict__ out)            // (B, 32, 128)
{
    const int bh  = blockIdx.x;
    const int b   = bh >> 5;
    const int h   = bh & 31;
    const int tid = threadIdx.x;

    __shared__ float w_q[DDIM], w_k[DDIM], v_s[DDIM];
    __shared__ float pq[8][DDIM], pk[8][DDIM];
    __shared__ float part[4][3];

    // ---- prologue loads (tid<128 lanes do the per-channel work) ----
    float cs_q[3], cs_k[3], cs_v[3];
    float4 cw_q = {0,0,0,0}, cw_k = {0,0,0,0}, cw_v = {0,0,0,0};
    float mx_q = 0.f, mx_k = 0.f, mx_v = 0.f, fg = 0.f, dtb = 0.f;
    cs_q[0]=cs_q[1]=cs_q[2]=0.f; cs_k[0]=cs_k[1]=cs_k[2]=0.f; cs_v[0]=cs_v[1]=cs_v[2]=0.f;

    const float betav = beta[b * NHV + h];
    const float alog  = A_log[h];

    if (tid < DDIM) {
        const int cq = h * DDIM + tid;
        const int ck = (NHK + h) * DDIM + tid;
        const int cv = (2 * NHK + h) * DDIM + tid;
        const size_t b3 = (size_t)b * QKVC * 3;
        const size_t b1 = (size_t)b * QKVC;

        #pragma unroll
        for (int j = 0; j < 3; ++j) {
            cs_q[j] = cstate[b3 + (size_t)cq * 3 + j];
            cs_k[j] = cstate[b3 + (size_t)ck * 3 + j];
            cs_v[j] = cstate[b3 + (size_t)cv * 3 + j];
        }
        cw_q = *reinterpret_cast<const float4*>(cweight + (size_t)cq * 4);
        cw_k = *reinterpret_cast<const float4*>(cweight + (size_t)ck * 4);
        cw_v = *reinterpret_cast<const float4*>(cweight + (size_t)cv * 4);
        mx_q = mixed[b1 + cq];
        mx_k = mixed[b1 + ck];
        mx_v = mixed[b1 + cv];
        fg   = fgate[(size_t)b * (NHV * DDIM) + h * DDIM + tid];
        dtb  = dt_bias[h * DDIM + tid];
    }

    // ---- conv + SiLU ----
    float xq = 0.f, xk = 0.f, xv = 0.f;
    if (tid < DDIM) {
        xq = silu_f(cs_q[0]*cw_q.x + cs_q[1]*cw_q.y + cs_q[2]*cw_q.z + mx_q*cw_q.w);
        xk = silu_f(cs_k[0]*cw_k.x + cs_k[1]*cw_k.y + cs_k[2]*cw_k.z + mx_k*cw_k.w);
        xv = silu_f(cs_v[0]*cw_v.x + cs_v[1]*cw_v.y + cs_v[2]*cw_v.z + mx_v*cw_v.w);
    }

    // ---- wave-level reductions (|q|^2, |k|^2, q.k), one barrier ----
    float a0 = xq * xq, a1 = xk * xk, a2 = xq * xk;
    #pragma unroll
    for (int off = 32; off; off >>= 1) {
        a0 += __shfl_xor(a0, off);
        a1 += __shfl_xor(a1, off);
        a2 += __shfl_xor(a2, off);
    }
    const int wid = tid >> 6;
    if ((tid & 63) == 0) { part[wid][0] = a0; part[wid][1] = a1; part[wid][2] = a2; }
    __syncthreads();
    const float q2  = part[0][0] + part[1][0];
    const float k2  = part[0][1] + part[1][1];
    const float qkd = part[0][2] + part[1][2];

    const float dscale = 0.08838834764831845f;   // 1/sqrt(128)
    const float rq = rsqrtf(q2 + 1e-6f);
    const float rk = rsqrtf(k2 + 1e-6f);
    const float qk = qkd * rq * rk * dscale;     // qn . kn
    const float bsig = sigmoid_f(betav);

    if (tid < DDIM) {
        const float g  = -expf(alog) * softplus_f(fg + dtb);
        const float eg = expf(g);
        w_q[tid] = xq * rq * dscale * eg;
        w_k[tid] = xk * rk * eg;
        v_s[tid] = xv;
    }
    __syncthreads();

    // ---- main stream: copy-bench-shaped linear sweep of S0[b,h] ----
    // iter i: block reads rows i*8 .. i*8+7 (4 KB contiguous);
    // each wave reads one contiguous 1 KB line. Thread owns rows {i*8+rp},
    // fixed 4-column slice col4.
    const float* Sb = ssm + (size_t)bh * (DDIM * DDIM);
    const int rp   = tid >> 5;         // row phase 0..7
    const int col4 = (tid & 31) * 4;   // 4 consecutive columns

    float4 accq = {0.f, 0.f, 0.f, 0.f};
    float4 acck = {0.f, 0.f, 0.f, 0.f};
    #pragma unroll 4
    for (int i = 0; i < 16; ++i) {
        const int row = i * 8 + rp;
        const f32x4 sv = __builtin_nontemporal_load(
            reinterpret_cast<const f32x4*>(Sb + (size_t)row * DDIM + col4));
        const float wq = w_q[row];     // 32-lane broadcast read
        const float wk = w_k[row];
        accq.x = fmaf(wq, sv.x, accq.x); accq.y = fmaf(wq, sv.y, accq.y);
        accq.z = fmaf(wq, sv.z, accq.z); accq.w = fmaf(wq, sv.w, accq.w);
        acck.x = fmaf(wk, sv.x, acck.x); acck.y = fmaf(wk, sv.y, acck.y);
        acck.z = fmaf(wk, sv.z, acck.z); acck.w = fmaf(wk, sv.w, acck.w);
    }
    *reinterpret_cast<float4*>(&pq[rp][col4]) = accq;
    *reinterpret_cast<float4*>(&pk[rp][col4]) = acck;
    __syncthreads();

    // ---- epilogue: combine partials, delta-rule correction, store ----
    if (tid < DDIM) {
        float aq = 0.f, ak = 0.f;
        #pragma unroll
        for (int g = 0; g < 8; ++g) { aq += pq[g][tid]; ak += pk[g][tid]; }
        const float o = aq + qk * (v_s[tid] - ak) * bsig;
        out[(size_t)bh * DDIM + tid] = o;
    }
}

extern "C" void kernel_launch(void* const* d_in, const int* in_sizes, int n_in,
                              void* d_out, int out_size, void* d_ws, size_t ws_size,
                              hipStream_t stream) {
    const float* mixed   = (const float*)d_in[0];
    const float* fgate   = (const float*)d_in[1];
    const float* beta    = (const float*)d_in[2];
    const float* cstate  = (const float*)d_in[3];
    const float* cweight = (const float*)d_in[4];
    const float* ssm     = (const float*)d_in[5];
    const float* A_log   = (const float*)d_in[6];
    const float* dt_bias = (const float*)d_in[7];
    float* out = (float*)d_out;

    kda_decode_kernel<<<NB * NHV, 256, 0, stream>>>(
        mixed, fgate, beta, cstate, cweight, ssm, A_log, dt_bias, out);
}